// Round 2
// baseline (993.552 us; speedup 1.0000x reference)
//
#include <hip/hip_runtime.h>
#include <math.h>

#define HID   1024
#define HID2  2048
#define BATCH 64
#define SRC   512
#define MROWS (SRC * BATCH)   // 32768 rows; row m = s*64 + b
#define NEGV  (-1e10f)

typedef int  i4v __attribute__((ext_vector_type(4)));   // 4 i32 = v4i32
typedef float f4v __attribute__((ext_vector_type(4)));

// ---------------------------------------------------------------------------
// K0: zero the energy accumulator (ws is poisoned 0xAA before every launch)
// ---------------------------------------------------------------------------
__global__ void zero_energy(float* __restrict__ e) {
    int i = blockIdx.x * 256 + threadIdx.x;
    if (i < MROWS) e[i] = 0.f;
}

// ---------------------------------------------------------------------------
// K1a: two-digit i8 fixed-point split (for A):  x ~= q1/s1 + q2/s2
// ---------------------------------------------------------------------------
__global__ void split_i8(const float* __restrict__ src,
                         signed char* __restrict__ q1b,
                         signed char* __restrict__ q2b,
                         int n16, float s1, float inv_s1, float s2) {
    int i = blockIdx.x * 256 + threadIdx.x;
    if (i >= n16) return;
    const float4* s = (const float4*)src + (size_t)i * 4;
    float v[16];
    *(float4*)&v[0]  = s[0];
    *(float4*)&v[4]  = s[1];
    *(float4*)&v[8]  = s[2];
    *(float4*)&v[12] = s[3];
    unsigned w1[4], w2[4];
#pragma unroll
    for (int p = 0; p < 4; ++p) {
        unsigned a1 = 0, a2 = 0;
#pragma unroll
        for (int j = 0; j < 4; ++j) {
            float a  = v[p * 4 + j];
            float q1 = rintf(a * s1);
            q1 = fminf(fmaxf(q1, -127.f), 127.f);
            float r  = fmaf(q1, -inv_s1, a);        // exact residual
            float q2 = rintf(r * s2);
            q2 = fminf(fmaxf(q2, -127.f), 127.f);
            a1 |= ((unsigned)((int)q1 & 0xff)) << (8 * j);
            a2 |= ((unsigned)((int)q2 & 0xff)) << (8 * j);
        }
        w1[p] = a1; w2[p] = a2;
    }
    ((uint4*)q1b)[i] = make_uint4(w1[0], w1[1], w1[2], w1[3]);
    ((uint4*)q2b)[i] = make_uint4(w2[0], w2[1], w2[2], w2[3]);
}

// ---------------------------------------------------------------------------
// K1b: single-digit i8 quant (for B)
// ---------------------------------------------------------------------------
__global__ void quant_i8(const float* __restrict__ src,
                         signed char* __restrict__ qb,
                         int n16, float s) {
    int i = blockIdx.x * 256 + threadIdx.x;
    if (i >= n16) return;
    const float4* sp = (const float4*)src + (size_t)i * 4;
    float v[16];
    *(float4*)&v[0]  = sp[0];
    *(float4*)&v[4]  = sp[1];
    *(float4*)&v[8]  = sp[2];
    *(float4*)&v[12] = sp[3];
    unsigned w[4];
#pragma unroll
    for (int p = 0; p < 4; ++p) {
        unsigned a = 0;
#pragma unroll
        for (int j = 0; j < 4; ++j) {
            float q = rintf(v[p * 4 + j] * s);
            q = fminf(fmaxf(q, -127.f), 127.f);
            a |= ((unsigned)((int)q & 0xff)) << (8 * j);
        }
        w[p] = a;
    }
    ((uint4*)qb)[i] = make_uint4(w[0], w[1], w[2], w[3]);
}

// ---------------------------------------------------------------------------
// K2: Wh[b][h] = hidden[b,:] . W_w[h,:] + W_b[h]   (fp32, small)
// ---------------------------------------------------------------------------
__global__ void wh_kernel(const float* __restrict__ hidden,
                          const float* __restrict__ W_w,
                          const float* __restrict__ W_b,
                          float* __restrict__ Wh) {
    __shared__ float sh[HID];
    const int b = blockIdx.y;
    const int t = threadIdx.x;
    for (int k = t; k < HID; k += 256) sh[k] = hidden[b * HID + k];
    __syncthreads();
    const int h = blockIdx.x * 256 + t;
    const float* wr = W_w + (size_t)h * HID;
    float acc = 0.f;
    for (int k = 0; k < HID; k += 4) {
        float4 w = *(const float4*)(wr + k);
        acc += sh[k] * w.x + sh[k+1] * w.y + sh[k+2] * w.z + sh[k+3] * w.w;
    }
    Wh[b * HID + h] = acc + W_b[h];
}

// ---------------------------------------------------------------------------
// fast tanh: tanh(x) = sign(x) * (1 - t)/(1 + t), t = e^{-2|x|}  (stable)
// ---------------------------------------------------------------------------
static __device__ __forceinline__ float tanh_fast(float x) {
    float ax = fabsf(x);
    float t  = __expf(-2.f * ax);
    float r  = __fdividef(1.f - t, 1.f + t);
    return copysignf(r, x);
}

// ---------------------------------------------------------------------------
// K3: i8 MFMA GEMM + fused tanh/v-dot epilogue (2-term scheme).
//   a ~= A1/16 + A2/4096 ; b ~= B1/5746
// Tile 128x128, 4 waves (2x2 of 64x64), 16x16x64 i8 MFMA, BK=64.
//
// Round-2 restructure (T3-min + T2 + T5):
//  * Double-buffered LDS (2 x 24 KB) + prefetch: issue next K-tile's
//    global_load_lds BEFORE current ds_read+MFMA; single vmcnt(0)+raw
//    s_barrier per K-step at the END -> load latency hides under compute
//    (old: __syncthreads drained vmcnt(0) serially every step).
//  * LDS XOR swizzle, both-sides (rule #21): gload_lds writes linearly, so
//    the 16B-slot permutation slot^=(row>>1)&3 is applied to the GLOBAL
//    source address on stage and to the read address. Kills the measured
//    8-way bank conflict (1.26e7/dispatch) -> 2-way (free).
//  * s_setprio(1) around the MFMA cluster.
// XCD swizzle (round 1) kept: FETCH 529->102 MB verified.
// ---------------------------------------------------------------------------
__global__ __launch_bounds__(256, 3)
void gemm_energy(const signed char* __restrict__ A1,   // [R][2048]
                 const signed char* __restrict__ A2,
                 const signed char* __restrict__ B1,   // [1024][2048]
                 const float* __restrict__ Ub,
                 const float* __restrict__ vw,
                 const float* __restrict__ Wh,         // [64][1024]
                 float* __restrict__ energy,           // [MROWS]
                 int m_base)
{
    // [2 dbuf][3 tiles][128 rows][64 bytes] = 48 KB
    __shared__ signed char sAll[2 * 3 * 8192];

    const int tid  = threadIdx.x;
    const int wave = tid >> 6;
    const int lane = tid & 63;

    // ---- XCD-aware bijective swizzle (nwg is a multiple of 64) ----
    const int nwg = (int)(gridDim.x * gridDim.y);          // 8 * (R/128)
    const int bid = (int)(blockIdx.y * gridDim.x + blockIdx.x);
    const int cpx = nwg >> 3;                              // chunk per XCD
    const int swz = (bid & 7) * cpx + (bid >> 3);
    const int h0 = (swz & 7) * 128;                        // h fastest
    const int m0 = (swz >> 3) * 128;

    const int wm = wave & 1;
    const int wn = wave >> 1;

    i4v c1[4][4], c2[4][4];
#pragma unroll
    for (int i = 0; i < 4; i++)
#pragma unroll
        for (int j = 0; j < 4; j++) {
            c1[i][j] = (i4v){0, 0, 0, 0};
            c2[i][j] = (i4v){0, 0, 0, 0};
        }

    const int ar = lane & 15;                         // row within a 16-tile
    // read-side swizzled slot: slot' = (lane>>4) ^ ((row>>1)&3); row bits 1..2
    // come only from ar (i*16, wm*64 contribute multiples of 4 to row>>1).
    const int ko = (((lane >> 4) ^ ((ar >> 1) & 3)) * 16);

    // ---- stage macro: 3 tiles into dbuf CB (byte base), K-offset K0 ----
    // LDS dest is linear (HW: wave-uniform base + lane*16); the slot
    // permutation is applied to the global source byte offset instead.
#define STAGE_TILES(CB, K0)                                                   \
    {                                                                         \
        _Pragma("unroll")                                                     \
        for (int it = 0; it < 2; ++it) {                                      \
            const int f    = it * 256 + tid;                                  \
            const int row  = f >> 2;                                          \
            const int inn  = (((f & 3) ^ ((row >> 1) & 3))) * 16;             \
            const int loff = (CB) + (it * 256 + wave * 64) * 16;              \
            const signed char* ga = A1 + (size_t)(m0 + row) * HID2 + (K0) + inn; \
            __builtin_amdgcn_global_load_lds(                                 \
                (const __attribute__((address_space(1))) unsigned int*)ga,    \
                (__attribute__((address_space(3))) unsigned int*)(sAll + loff), \
                16, 0, 0);                                                    \
            const signed char* gb = A2 + (size_t)(m0 + row) * HID2 + (K0) + inn; \
            __builtin_amdgcn_global_load_lds(                                 \
                (const __attribute__((address_space(1))) unsigned int*)gb,    \
                (__attribute__((address_space(3))) unsigned int*)(sAll + 8192 + loff), \
                16, 0, 0);                                                    \
            const signed char* gc = B1 + (size_t)(h0 + row) * HID2 + (K0) + inn; \
            __builtin_amdgcn_global_load_lds(                                 \
                (const __attribute__((address_space(1))) unsigned int*)gc,    \
                (__attribute__((address_space(3))) unsigned int*)(sAll + 16384 + loff), \
                16, 0, 0);                                                    \
        }                                                                     \
    }

    // ---- prologue: fill buffer 0, wait, sync ----
    STAGE_TILES(0, 0);
    asm volatile("s_waitcnt vmcnt(0)" ::: "memory");
    __builtin_amdgcn_s_barrier();

    int cur = 0;
    for (int ks = 0; ks < 32; ++ks) {
        const int cb = cur * 24576;
        // 1) issue next K-tile's loads into the other buffer (overlaps below)
        if (ks + 1 < 32) STAGE_TILES(cb ^ 24576, (ks + 1) * 64);

        // 2) ds_read current fragments (swizzled slots, 2-way max conflict)
        i4v a1[4], a2[4], b1[4];
#pragma unroll
        for (int i = 0; i < 4; ++i) {
            const int ra = cb + (wm * 64 + i * 16 + ar) * 64 + ko;
            const int rb = cb + 16384 + (wn * 64 + i * 16 + ar) * 64 + ko;
            a1[i] = *(const i4v*)&sAll[ra];
            a2[i] = *(const i4v*)&sAll[8192 + ra];
            b1[i] = *(const i4v*)&sAll[rb];
        }
        asm volatile("s_waitcnt lgkmcnt(0)" ::: "memory");
        __builtin_amdgcn_sched_barrier(0);

        // 3) MFMA cluster
        __builtin_amdgcn_s_setprio(1);
#pragma unroll
        for (int i = 0; i < 4; ++i)
#pragma unroll
            for (int j = 0; j < 4; ++j) {
                c1[i][j] = __builtin_amdgcn_mfma_i32_16x16x64_i8(a1[i], b1[j], c1[i][j], 0, 0, 0);
                c2[i][j] = __builtin_amdgcn_mfma_i32_16x16x64_i8(a2[i], b1[j], c2[i][j], 0, 0, 0);
            }
        __builtin_amdgcn_s_setprio(0);

        // 4) next buffer ready + all waves done reading cur
        asm volatile("s_waitcnt vmcnt(0)" ::: "memory");
        __builtin_amdgcn_s_barrier();
        cur ^= 1;
    }
#undef STAGE_TILES

    // ---- fused epilogue: C/D layout col=lane&15, row=(lane>>4)*4+reg ----
    const int col = lane & 15;
    const int rg  = lane >> 4;
    const float invs = 1.f / (4096.f * 5746.f);   // c2-scale; c1 carries x256
    float vj[4], ubj[4];
#pragma unroll
    for (int j = 0; j < 4; ++j) {
        const int hc = h0 + wn * 64 + j * 16 + col;
        vj[j]  = vw[hc];
        ubj[j] = Ub[hc];
    }
#pragma unroll
    for (int i = 0; i < 4; ++i) {
#pragma unroll
        for (int r = 0; r < 4; ++r) {
            const int mm = m0 + wm * 64 + i * 16 + rg * 4 + r;
            const int b  = (m_base + mm) & 63;
            const float* whr = Wh + b * HID + h0 + wn * 64 + col;
            float e = 0.f;
#pragma unroll
            for (int j = 0; j < 4; ++j) {
                float C = fmaf((float)c1[i][j][r], 256.f, (float)c2[i][j][r]) * invs;
                float x = C + ubj[j] + whr[j * 16];
                e += vj[j] * tanh_fast(x);
            }
            e += __shfl_xor(e, 1, 64);
            e += __shfl_xor(e, 2, 64);
            e += __shfl_xor(e, 4, 64);
            e += __shfl_xor(e, 8, 64);
            if (col == 0) atomicAdd(&energy[m_base + mm], e);
        }
    }
}

// ---------------------------------------------------------------------------
// K4: masked softmax over s per b. energy layout [s*64+b], out [b][s].
// ---------------------------------------------------------------------------
__global__ void softmax_kernel(const float* __restrict__ energy,
                               const int* __restrict__ mask,
                               float* __restrict__ out) {
    const int b = blockIdx.x;
    const int t = threadIdx.x;
    __shared__ float wmax[4], wsum[4];

    float x0 = energy[t * 64 + b];
    float x1 = energy[(t + 256) * 64 + b];
    float e0 = mask[b * SRC + t]       ? NEGV : x0;
    float e1 = mask[b * SRC + t + 256] ? NEGV : x1;

    float mx = fmaxf(e0, e1);
#pragma unroll
    for (int off = 1; off < 64; off <<= 1)
        mx = fmaxf(mx, __shfl_xor(mx, off, 64));
    const int wid = t >> 6, lane = t & 63;
    if (lane == 0) wmax[wid] = mx;
    __syncthreads();
    mx = fmaxf(fmaxf(wmax[0], wmax[1]), fmaxf(wmax[2], wmax[3]));

    float p0 = expf(e0 - mx), p1 = expf(e1 - mx);
    float sum = p0 + p1;
#pragma unroll
    for (int off = 1; off < 64; off <<= 1)
        sum += __shfl_xor(sum, off, 64);
    if (lane == 0) wsum[wid] = sum;
    __syncthreads();
    sum = wsum[0] + wsum[1] + wsum[2] + wsum[3];
    const float inv = 1.f / sum;
    out[b * SRC + t]       = p0 * inv;
    out[b * SRC + t + 256] = p1 * inv;
}

// ---------------------------------------------------------------------------
extern "C" void kernel_launch(void* const* d_in, const int* in_sizes, int n_in,
                              void* d_out, int out_size, void* d_ws, size_t ws_size,
                              hipStream_t stream) {
    const float* hidden = (const float*)d_in[0];   // [64, 1024]
    const float* enc    = (const float*)d_in[1];   // [512*64, 2048] flat rows
    const int*   mask   = (const int*)d_in[2];     // [64, 512]
    const float* W_w    = (const float*)d_in[3];   // [1024, 1024]
    const float* W_b    = (const float*)d_in[4];   // [1024]
    const float* U_w    = (const float*)d_in[5];   // [1024, 2048]
    const float* U_b    = (const float*)d_in[6];   // [1024]
    const float* v_w    = (const float*)d_in[7];   // [1, 1024]
    float* out = (float*)d_out;                    // [64, 512]

    // workspace layout
    char* p = (char*)d_ws;
    float* Wh     = (float*)p;             p += (size_t)BATCH * HID * 4;
    float* energy = (float*)p;             p += (size_t)MROWS * 4;
    signed char* B1 = (signed char*)p;     p += (size_t)HID * HID2;
    const size_t fixed = (size_t)(p - (char*)d_ws);

    // pick largest A-chunk R (multiple of 128 rows): bytes = 2 * R * 2048
    int R = 1024;
    const int cand[6] = {32768, 16384, 8192, 4096, 2048, 1024};
    for (int c = 0; c < 6; ++c) {
        if (fixed + (size_t)cand[c] * HID2 * 2 <= ws_size) { R = cand[c]; break; }
    }
    signed char* A1 = (signed char*)p;
    signed char* A2 = A1 + (size_t)R * HID2;

    // scales: a ~= A1/16 + A2/4096 ; b ~= B1/5746  (max-range single digit)
    const float Sa1 = 16.f, iSa1 = 1.f / 16.f, Sa2 = 4096.f;
    const float Sb1 = 5746.f;

    hipLaunchKernelGGL(zero_energy, dim3(MROWS / 256), dim3(256), 0, stream, energy);
    hipLaunchKernelGGL(wh_kernel, dim3(4, BATCH), dim3(256), 0, stream,
                       hidden, W_w, W_b, Wh);
    {   // quantize U_w once (8 MB fp32 -> 2 MB i8)
        const int n16 = HID * HID2 / 16;
        hipLaunchKernelGGL(quant_i8, dim3((n16 + 255) / 256), dim3(256), 0, stream,
                           U_w, B1, n16, Sb1);
    }
    for (int c0 = 0; c0 < MROWS; c0 += R) {
        const int n16 = R * HID2 / 16;
        hipLaunchKernelGGL(split_i8, dim3((n16 + 255) / 256), dim3(256), 0, stream,
                           enc + (size_t)c0 * HID2, A1, A2, n16, Sa1, iSa1, Sa2);
        hipLaunchKernelGGL(gemm_energy, dim3(HID / 128, R / 128), dim3(256), 0, stream,
                           A1, A2, B1, U_b, v_w, Wh, energy, c0);
    }
    hipLaunchKernelGGL(softmax_kernel, dim3(BATCH), dim3(256), 0, stream,
                       energy, mask, out);
}

// Round 3
// 603.978 us; speedup vs baseline: 1.6450x; 1.6450x over previous
//
#include <hip/hip_runtime.h>
#include <math.h>

#define HID   1024
#define HID2  2048
#define BATCH 64
#define SRC   512
#define MROWS (SRC * BATCH)   // 32768 rows; row m = s*64 + b
#define NEGV  (-1e10f)

typedef int  i4v __attribute__((ext_vector_type(4)));   // 4 i32 = v4i32
typedef float f4v __attribute__((ext_vector_type(4)));

// ---------------------------------------------------------------------------
// K0: zero the energy accumulator (ws is poisoned 0xAA before every launch)
// ---------------------------------------------------------------------------
__global__ void zero_energy(float* __restrict__ e) {
    int i = blockIdx.x * 256 + threadIdx.x;
    if (i < MROWS) e[i] = 0.f;
}

// ---------------------------------------------------------------------------
// K1a: two-digit i8 fixed-point split (for A):  x ~= q1/s1 + q2/s2
// ---------------------------------------------------------------------------
__global__ void split_i8(const float* __restrict__ src,
                         signed char* __restrict__ q1b,
                         signed char* __restrict__ q2b,
                         int n16, float s1, float inv_s1, float s2) {
    int i = blockIdx.x * 256 + threadIdx.x;
    if (i >= n16) return;
    const float4* s = (const float4*)src + (size_t)i * 4;
    float v[16];
    *(float4*)&v[0]  = s[0];
    *(float4*)&v[4]  = s[1];
    *(float4*)&v[8]  = s[2];
    *(float4*)&v[12] = s[3];
    unsigned w1[4], w2[4];
#pragma unroll
    for (int p = 0; p < 4; ++p) {
        unsigned a1 = 0, a2 = 0;
#pragma unroll
        for (int j = 0; j < 4; ++j) {
            float a  = v[p * 4 + j];
            float q1 = rintf(a * s1);
            q1 = fminf(fmaxf(q1, -127.f), 127.f);
            float r  = fmaf(q1, -inv_s1, a);        // exact residual
            float q2 = rintf(r * s2);
            q2 = fminf(fmaxf(q2, -127.f), 127.f);
            a1 |= ((unsigned)((int)q1 & 0xff)) << (8 * j);
            a2 |= ((unsigned)((int)q2 & 0xff)) << (8 * j);
        }
        w1[p] = a1; w2[p] = a2;
    }
    ((uint4*)q1b)[i] = make_uint4(w1[0], w1[1], w1[2], w1[3]);
    ((uint4*)q2b)[i] = make_uint4(w2[0], w2[1], w2[2], w2[3]);
}

// ---------------------------------------------------------------------------
// K1b: single-digit i8 quant (for B)
// ---------------------------------------------------------------------------
__global__ void quant_i8(const float* __restrict__ src,
                         signed char* __restrict__ qb,
                         int n16, float s) {
    int i = blockIdx.x * 256 + threadIdx.x;
    if (i >= n16) return;
    const float4* sp = (const float4*)src + (size_t)i * 4;
    float v[16];
    *(float4*)&v[0]  = sp[0];
    *(float4*)&v[4]  = sp[1];
    *(float4*)&v[8]  = sp[2];
    *(float4*)&v[12] = sp[3];
    unsigned w[4];
#pragma unroll
    for (int p = 0; p < 4; ++p) {
        unsigned a = 0;
#pragma unroll
        for (int j = 0; j < 4; ++j) {
            float q = rintf(v[p * 4 + j] * s);
            q = fminf(fmaxf(q, -127.f), 127.f);
            a |= ((unsigned)((int)q & 0xff)) << (8 * j);
        }
        w[p] = a;
    }
    ((uint4*)qb)[i] = make_uint4(w[0], w[1], w[2], w[3]);
}

// ---------------------------------------------------------------------------
// K2: Wh[b][h] = hidden[b,:] . W_w[h,:] + W_b[h]   (fp32, small)
// ---------------------------------------------------------------------------
__global__ void wh_kernel(const float* __restrict__ hidden,
                          const float* __restrict__ W_w,
                          const float* __restrict__ W_b,
                          float* __restrict__ Wh) {
    __shared__ float sh[HID];
    const int b = blockIdx.y;
    const int t = threadIdx.x;
    for (int k = t; k < HID; k += 256) sh[k] = hidden[b * HID + k];
    __syncthreads();
    const int h = blockIdx.x * 256 + t;
    const float* wr = W_w + (size_t)h * HID;
    float acc = 0.f;
    for (int k = 0; k < HID; k += 4) {
        float4 w = *(const float4*)(wr + k);
        acc += sh[k] * w.x + sh[k+1] * w.y + sh[k+2] * w.z + sh[k+3] * w.w;
    }
    Wh[b * HID + h] = acc + W_b[h];
}

// ---------------------------------------------------------------------------
// fast tanh: tanh(x) = sign(x) * (1 - t)/(1 + t), t = e^{-2|x|}  (stable)
// ---------------------------------------------------------------------------
static __device__ __forceinline__ float tanh_fast(float x) {
    float ax = fabsf(x);
    float t  = __expf(-2.f * ax);
    float r  = __fdividef(1.f - t, 1.f + t);
    return copysignf(r, x);
}

// ---------------------------------------------------------------------------
// K3: i8 MFMA GEMM + fused tanh/v-dot epilogue (2-term scheme).
//   a ~= A1/16 + A2/4096 ; b ~= B1/5746
// Tile 128x128, 4 waves (2x2 of 64x64), 16x16x64 i8 MFMA, BK=64.
//
// Structure (round 3):
//  * Double-buffered LDS (2 x 24 KB) + prefetch-before-compute; single
//    vmcnt(0)+raw s_barrier per K-step at the END.
//  * Both-sides LDS XOR swizzle (verified round 2: SQ_LDS_BANK_CONFLICT
//    1.26e7 -> 0): gload_lds writes linearly; the 16B-slot permutation
//    slot^=(row>>1)&3 is applied to the GLOBAL source address on stage and
//    to the ds_read address.
//  * s_setprio(1) around the MFMA cluster.
//  * __launch_bounds__(256, 2): round 2's (256,3) capped regs at ~170/thread
//    vs the ~224 this kernel needs (128 acc + 48 frag) -> accumulators
//    spilled to scratch (WRITE_SIZE 8 MB -> 960 MB, 3x regression). 2
//    waves/EU restores the 256-reg budget; accumulators live in AGPRs.
// XCD swizzle (round 1) kept: FETCH 529->102 MB verified.
// ---------------------------------------------------------------------------
__global__ __launch_bounds__(256, 2)
void gemm_energy(const signed char* __restrict__ A1,   // [R][2048]
                 const signed char* __restrict__ A2,
                 const signed char* __restrict__ B1,   // [1024][2048]
                 const float* __restrict__ Ub,
                 const float* __restrict__ vw,
                 const float* __restrict__ Wh,         // [64][1024]
                 float* __restrict__ energy,           // [MROWS]
                 int m_base)
{
    // [2 dbuf][3 tiles][128 rows][64 bytes] = 48 KB
    __shared__ signed char sAll[2 * 3 * 8192];

    const int tid  = threadIdx.x;
    const int wave = tid >> 6;
    const int lane = tid & 63;

    // ---- XCD-aware bijective swizzle (nwg is a multiple of 64) ----
    const int nwg = (int)(gridDim.x * gridDim.y);          // 8 * (R/128)
    const int bid = (int)(blockIdx.y * gridDim.x + blockIdx.x);
    const int cpx = nwg >> 3;                              // chunk per XCD
    const int swz = (bid & 7) * cpx + (bid >> 3);
    const int h0 = (swz & 7) * 128;                        // h fastest
    const int m0 = (swz >> 3) * 128;

    const int wm = wave & 1;
    const int wn = wave >> 1;

    i4v c1[4][4], c2[4][4];
#pragma unroll
    for (int i = 0; i < 4; i++)
#pragma unroll
        for (int j = 0; j < 4; j++) {
            c1[i][j] = (i4v){0, 0, 0, 0};
            c2[i][j] = (i4v){0, 0, 0, 0};
        }

    const int ar = lane & 15;                         // row within a 16-tile
    // read-side swizzled slot: slot' = (lane>>4) ^ ((row>>1)&3); row bits 1..2
    // come only from ar (i*16, wm*64 contribute multiples of 4 to row>>1).
    const int ko = (((lane >> 4) ^ ((ar >> 1) & 3)) * 16);

    // ---- stage macro: 3 tiles into dbuf CB (byte base), K-offset K0 ----
    // LDS dest is linear (HW: wave-uniform base + lane*16); the slot
    // permutation is applied to the global source byte offset instead.
#define STAGE_TILES(CB, K0)                                                   \
    {                                                                         \
        _Pragma("unroll")                                                     \
        for (int it = 0; it < 2; ++it) {                                      \
            const int f    = it * 256 + tid;                                  \
            const int row  = f >> 2;                                          \
            const int inn  = (((f & 3) ^ ((row >> 1) & 3))) * 16;             \
            const int loff = (CB) + (it * 256 + wave * 64) * 16;              \
            const signed char* ga = A1 + (size_t)(m0 + row) * HID2 + (K0) + inn; \
            __builtin_amdgcn_global_load_lds(                                 \
                (const __attribute__((address_space(1))) unsigned int*)ga,    \
                (__attribute__((address_space(3))) unsigned int*)(sAll + loff), \
                16, 0, 0);                                                    \
            const signed char* gb = A2 + (size_t)(m0 + row) * HID2 + (K0) + inn; \
            __builtin_amdgcn_global_load_lds(                                 \
                (const __attribute__((address_space(1))) unsigned int*)gb,    \
                (__attribute__((address_space(3))) unsigned int*)(sAll + 8192 + loff), \
                16, 0, 0);                                                    \
            const signed char* gc = B1 + (size_t)(h0 + row) * HID2 + (K0) + inn; \
            __builtin_amdgcn_global_load_lds(                                 \
                (const __attribute__((address_space(1))) unsigned int*)gc,    \
                (__attribute__((address_space(3))) unsigned int*)(sAll + 16384 + loff), \
                16, 0, 0);                                                    \
        }                                                                     \
    }

    // ---- prologue: fill buffer 0, wait, sync ----
    STAGE_TILES(0, 0);
    asm volatile("s_waitcnt vmcnt(0)" ::: "memory");
    __builtin_amdgcn_s_barrier();

    int cur = 0;
    for (int ks = 0; ks < 32; ++ks) {
        const int cb = cur * 24576;
        // 1) issue next K-tile's loads into the other buffer (overlaps below)
        if (ks + 1 < 32) STAGE_TILES(cb ^ 24576, (ks + 1) * 64);

        // 2) ds_read current fragments (swizzled slots, conflict-free)
        i4v a1[4], a2[4], b1[4];
#pragma unroll
        for (int i = 0; i < 4; ++i) {
            const int ra = cb + (wm * 64 + i * 16 + ar) * 64 + ko;
            const int rb = cb + 16384 + (wn * 64 + i * 16 + ar) * 64 + ko;
            a1[i] = *(const i4v*)&sAll[ra];
            a2[i] = *(const i4v*)&sAll[8192 + ra];
            b1[i] = *(const i4v*)&sAll[rb];
        }
        asm volatile("s_waitcnt lgkmcnt(0)" ::: "memory");
        __builtin_amdgcn_sched_barrier(0);

        // 3) MFMA cluster
        __builtin_amdgcn_s_setprio(1);
#pragma unroll
        for (int i = 0; i < 4; ++i)
#pragma unroll
            for (int j = 0; j < 4; ++j) {
                c1[i][j] = __builtin_amdgcn_mfma_i32_16x16x64_i8(a1[i], b1[j], c1[i][j], 0, 0, 0);
                c2[i][j] = __builtin_amdgcn_mfma_i32_16x16x64_i8(a2[i], b1[j], c2[i][j], 0, 0, 0);
            }
        __builtin_amdgcn_s_setprio(0);

        // 4) next buffer ready + all waves done reading cur
        asm volatile("s_waitcnt vmcnt(0)" ::: "memory");
        __builtin_amdgcn_s_barrier();
        cur ^= 1;
    }
#undef STAGE_TILES

    // ---- fused epilogue: C/D layout col=lane&15, row=(lane>>4)*4+reg ----
    const int col = lane & 15;
    const int rg  = lane >> 4;
    const float invs = 1.f / (4096.f * 5746.f);   // c2-scale; c1 carries x256
    float vj[4], ubj[4];
#pragma unroll
    for (int j = 0; j < 4; ++j) {
        const int hc = h0 + wn * 64 + j * 16 + col;
        vj[j]  = vw[hc];
        ubj[j] = Ub[hc];
    }
#pragma unroll
    for (int i = 0; i < 4; ++i) {
#pragma unroll
        for (int r = 0; r < 4; ++r) {
            const int mm = m0 + wm * 64 + i * 16 + rg * 4 + r;
            const int b  = (m_base + mm) & 63;
            const float* whr = Wh + b * HID + h0 + wn * 64 + col;
            float e = 0.f;
#pragma unroll
            for (int j = 0; j < 4; ++j) {
                float C = fmaf((float)c1[i][j][r], 256.f, (float)c2[i][j][r]) * invs;
                float x = C + ubj[j] + whr[j * 16];
                e += vj[j] * tanh_fast(x);
            }
            e += __shfl_xor(e, 1, 64);
            e += __shfl_xor(e, 2, 64);
            e += __shfl_xor(e, 4, 64);
            e += __shfl_xor(e, 8, 64);
            if (col == 0) atomicAdd(&energy[m_base + mm], e);
        }
    }
}

// ---------------------------------------------------------------------------
// K4: masked softmax over s per b. energy layout [s*64+b], out [b][s].
// ---------------------------------------------------------------------------
__global__ void softmax_kernel(const float* __restrict__ energy,
                               const int* __restrict__ mask,
                               float* __restrict__ out) {
    const int b = blockIdx.x;
    const int t = threadIdx.x;
    __shared__ float wmax[4], wsum[4];

    float x0 = energy[t * 64 + b];
    float x1 = energy[(t + 256) * 64 + b];
    float e0 = mask[b * SRC + t]       ? NEGV : x0;
    float e1 = mask[b * SRC + t + 256] ? NEGV : x1;

    float mx = fmaxf(e0, e1);
#pragma unroll
    for (int off = 1; off < 64; off <<= 1)
        mx = fmaxf(mx, __shfl_xor(mx, off, 64));
    const int wid = t >> 6, lane = t & 63;
    if (lane == 0) wmax[wid] = mx;
    __syncthreads();
    mx = fmaxf(fmaxf(wmax[0], wmax[1]), fmaxf(wmax[2], wmax[3]));

    float p0 = expf(e0 - mx), p1 = expf(e1 - mx);
    float sum = p0 + p1;
#pragma unroll
    for (int off = 1; off < 64; off <<= 1)
        sum += __shfl_xor(sum, off, 64);
    if (lane == 0) wsum[wid] = sum;
    __syncthreads();
    sum = wsum[0] + wsum[1] + wsum[2] + wsum[3];
    const float inv = 1.f / sum;
    out[b * SRC + t]       = p0 * inv;
    out[b * SRC + t + 256] = p1 * inv;
}

// ---------------------------------------------------------------------------
extern "C" void kernel_launch(void* const* d_in, const int* in_sizes, int n_in,
                              void* d_out, int out_size, void* d_ws, size_t ws_size,
                              hipStream_t stream) {
    const float* hidden = (const float*)d_in[0];   // [64, 1024]
    const float* enc    = (const float*)d_in[1];   // [512*64, 2048] flat rows
    const int*   mask   = (const int*)d_in[2];     // [64, 512]
    const float* W_w    = (const float*)d_in[3];   // [1024, 1024]
    const float* W_b    = (const float*)d_in[4];   // [1024]
    const float* U_w    = (const float*)d_in[5];   // [1024, 2048]
    const float* U_b    = (const float*)d_in[6];   // [1024]
    const float* v_w    = (const float*)d_in[7];   // [1, 1024]
    float* out = (float*)d_out;                    // [64, 512]

    // workspace layout
    char* p = (char*)d_ws;
    float* Wh     = (float*)p;             p += (size_t)BATCH * HID * 4;
    float* energy = (float*)p;             p += (size_t)MROWS * 4;
    signed char* B1 = (signed char*)p;     p += (size_t)HID * HID2;
    const size_t fixed = (size_t)(p - (char*)d_ws);

    // pick largest A-chunk R (multiple of 128 rows): bytes = 2 * R * 2048
    int R = 1024;
    const int cand[6] = {32768, 16384, 8192, 4096, 2048, 1024};
    for (int c = 0; c < 6; ++c) {
        if (fixed + (size_t)cand[c] * HID2 * 2 <= ws_size) { R = cand[c]; break; }
    }
    signed char* A1 = (signed char*)p;
    signed char* A2 = A1 + (size_t)R * HID2;

    // scales: a ~= A1/16 + A2/4096 ; b ~= B1/5746  (max-range single digit)
    const float Sa1 = 16.f, iSa1 = 1.f / 16.f, Sa2 = 4096.f;
    const float Sb1 = 5746.f;

    hipLaunchKernelGGL(zero_energy, dim3(MROWS / 256), dim3(256), 0, stream, energy);
    hipLaunchKernelGGL(wh_kernel, dim3(4, BATCH), dim3(256), 0, stream,
                       hidden, W_w, W_b, Wh);
    {   // quantize U_w once (8 MB fp32 -> 2 MB i8)
        const int n16 = HID * HID2 / 16;
        hipLaunchKernelGGL(quant_i8, dim3((n16 + 255) / 256), dim3(256), 0, stream,
                           U_w, B1, n16, Sb1);
    }
    for (int c0 = 0; c0 < MROWS; c0 += R) {
        const int n16 = R * HID2 / 16;
        hipLaunchKernelGGL(split_i8, dim3((n16 + 255) / 256), dim3(256), 0, stream,
                           enc + (size_t)c0 * HID2, A1, A2, n16, Sa1, iSa1, Sa2);
        hipLaunchKernelGGL(gemm_energy, dim3(HID / 128, R / 128), dim3(256), 0, stream,
                           A1, A2, B1, U_b, v_w, Wh, energy, c0);
    }
    hipLaunchKernelGGL(softmax_kernel, dim3(BATCH), dim3(256), 0, stream,
                       energy, mask, out);
}

// Round 6
// 595.685 us; speedup vs baseline: 1.6679x; 1.0139x over previous
//
#include <hip/hip_runtime.h>
#include <math.h>

#define HID   1024
#define HID2  2048
#define BATCH 64
#define SRC   512
#define MROWS (SRC * BATCH)   // 32768 rows; row m = s*64 + b
#define NEGV  (-1e10f)

typedef int  i4v __attribute__((ext_vector_type(4)));   // 4 i32 = v4i32
typedef float f4v __attribute__((ext_vector_type(4)));

// ---------------------------------------------------------------------------
// K0: zero the energy accumulator (ws is poisoned 0xAA before every launch)
// ---------------------------------------------------------------------------
__global__ void zero_energy(float* __restrict__ e) {
    int i = blockIdx.x * 256 + threadIdx.x;
    if (i < MROWS) e[i] = 0.f;
}

// ---------------------------------------------------------------------------
// K1a: two-digit i8 fixed-point split (for A):  x ~= q1/s1 + q2/s2
// Grid-stride; one float4 per iter: 16B/lane coalesced reads, 4B/lane writes.
// ---------------------------------------------------------------------------
__global__ void split_i8(const float* __restrict__ src,
                         signed char* __restrict__ q1b,
                         signed char* __restrict__ q2b,
                         int n4, float s1, float inv_s1, float s2) {
    const float4* s4 = (const float4*)src;
    unsigned* o1 = (unsigned*)q1b;
    unsigned* o2 = (unsigned*)q2b;
    for (int i = blockIdx.x * 256 + threadIdx.x; i < n4; i += gridDim.x * 256) {
        float4 v = s4[i];
        float vv[4] = {v.x, v.y, v.z, v.w};
        unsigned a1 = 0, a2 = 0;
#pragma unroll
        for (int j = 0; j < 4; ++j) {
            float a  = vv[j];
            float q1 = rintf(a * s1);
            q1 = fminf(fmaxf(q1, -127.f), 127.f);
            float r  = fmaf(q1, -inv_s1, a);        // exact residual
            float q2 = rintf(r * s2);
            q2 = fminf(fmaxf(q2, -127.f), 127.f);
            a1 |= ((unsigned)((int)q1 & 0xff)) << (8 * j);
            a2 |= ((unsigned)((int)q2 & 0xff)) << (8 * j);
        }
        o1[i] = a1;
        o2[i] = a2;
    }
}

// ---------------------------------------------------------------------------
// K1b: single-digit i8 quant (for B), grid-stride, coalesced
// ---------------------------------------------------------------------------
__global__ void quant_i8(const float* __restrict__ src,
                         signed char* __restrict__ qb,
                         int n4, float s) {
    const float4* s4 = (const float4*)src;
    unsigned* o = (unsigned*)qb;
    for (int i = blockIdx.x * 256 + threadIdx.x; i < n4; i += gridDim.x * 256) {
        float4 v = s4[i];
        float vv[4] = {v.x, v.y, v.z, v.w};
        unsigned a = 0;
#pragma unroll
        for (int j = 0; j < 4; ++j) {
            float q = rintf(vv[j] * s);
            q = fminf(fmaxf(q, -127.f), 127.f);
            a |= ((unsigned)((int)q & 0xff)) << (8 * j);
        }
        o[i] = a;
    }
}

// ---------------------------------------------------------------------------
// K2: Wh[b][h] = hidden[b,:] . W_w[h,:] + W_b[h]   (fp32, small)
// ---------------------------------------------------------------------------
__global__ void wh_kernel(const float* __restrict__ hidden,
                          const float* __restrict__ W_w,
                          const float* __restrict__ W_b,
                          float* __restrict__ Wh) {
    __shared__ float sh[HID];
    const int b = blockIdx.y;
    const int t = threadIdx.x;
    for (int k = t; k < HID; k += 256) sh[k] = hidden[b * HID + k];
    __syncthreads();
    const int h = blockIdx.x * 256 + t;
    const float* wr = W_w + (size_t)h * HID;
    float acc = 0.f;
    for (int k = 0; k < HID; k += 4) {
        float4 w = *(const float4*)(wr + k);
        acc += sh[k] * w.x + sh[k+1] * w.y + sh[k+2] * w.z + sh[k+3] * w.w;
    }
    Wh[b * HID + h] = acc + W_b[h];
}

// ---------------------------------------------------------------------------
// fast tanh: tanh(x) = sign(x) * (1 - t)/(1 + t), t = e^{-2|x|}  (stable)
// ---------------------------------------------------------------------------
static __device__ __forceinline__ float tanh_fast(float x) {
    float ax = fabsf(x);
    float t  = __expf(-2.f * ax);
    float r  = __fdividef(1.f - t, 1.f + t);
    return copysignf(r, x);
}

// ---------------------------------------------------------------------------
// K3: i8 MFMA GEMM + fused tanh/v-dot epilogue (2-term scheme).
//   a ~= A1/16 + A2/4096 ; b ~= B1/5746
// Tile 128x128, 4 waves (2x2 of 64x64), 16x16x64 i8 MFMA, BK=64.
//
// Round-6 = round-4 structure + SOUND BARRIER: the end-of-step sync is now a
// single asm volatile { s_waitcnt vmcnt(N) lgkmcnt(0) ; s_barrier } with
// "memory" clobber. The raw __builtin s_barrier has NO memory semantics in
// LLVM's model, so round-4's ds_reads/stages could migrate across it, and a
// wave could pass the barrier with its ds_reads of the about-to-be-restaged
// slot still in flight (LDS WAR race, potential cause of the container
// failures). lgkmcnt(0) sits AFTER the MFMAs -> no added stall (unlike
// round-3's read-to-MFMA pinning, the m141 lesson).
//
// Structure (T4 counted-vmcnt, compiler-scheduled interior):
//  * 3-deep LDS pipeline (3 x 24 KB = 72 KB). Per step: stage buf[k+2],
//    read buf[k], end with vmcnt(6) (NOT 0): buf[k+2]'s 6 loads stay in
//    flight across the barrier; only buf[k+1]'s must land. Loads get ~2
//    steps to cover L2/HBM latency.
//  * Both-sides LDS XOR swizzle (verified: SQ_LDS_BANK_CONFLICT 1.26e7->0).
//  * __launch_bounds__(256,2): 256-reg budget; accs live in unified AGPRs
//    (round 2: (256,3) -> 170-reg cap -> 1 GB scratch spill, 3x slower).
//  * XCD-aware swizzle (verified: FETCH 529->102 MB).
// ---------------------------------------------------------------------------
__global__ __launch_bounds__(256, 2)
void gemm_energy(const signed char* __restrict__ A1,   // [R][2048]
                 const signed char* __restrict__ A2,
                 const signed char* __restrict__ B1,   // [1024][2048]
                 const float* __restrict__ Ub,
                 const float* __restrict__ vw,
                 const float* __restrict__ Wh,         // [64][1024]
                 float* __restrict__ energy,           // [MROWS]
                 int m_base)
{
    // [3 pipe][3 mats][128 rows][64 bytes] = 72 KB
    __shared__ signed char sAll[3 * 3 * 8192];

    const int tid  = threadIdx.x;
    const int wave = tid >> 6;
    const int lane = tid & 63;

    // ---- XCD-aware bijective swizzle (nwg is a multiple of 8) ----
    const int nwg = (int)(gridDim.x * gridDim.y);          // 8 * (R/128)
    const int bid = (int)(blockIdx.y * gridDim.x + blockIdx.x);
    const int cpx = nwg >> 3;                              // chunk per XCD
    const int swz = (bid & 7) * cpx + (bid >> 3);
    const int h0 = (swz & 7) * 128;                        // h fastest
    const int m0 = (swz >> 3) * 128;

    const int wm = wave & 1;
    const int wn = wave >> 1;

    i4v c1[4][4], c2[4][4];
#pragma unroll
    for (int i = 0; i < 4; i++)
#pragma unroll
        for (int j = 0; j < 4; j++) {
            c1[i][j] = (i4v){0, 0, 0, 0};
            c2[i][j] = (i4v){0, 0, 0, 0};
        }

    const int ar = lane & 15;                         // row within a 16-tile
    // read-side swizzled slot: slot' = (lane>>4) ^ ((row>>1)&3); row bits 1..2
    // come only from ar (i*16, wm*64 contribute multiples of 4 to row>>1).
    const int ko = (((lane >> 4) ^ ((ar >> 1) & 3)) * 16);

    // ---- stage macro: 3 tiles into pipe slot CB (byte base), K-offset K0 ----
    // LDS dest is linear (HW: wave-uniform base + lane*16); the slot
    // permutation is applied to the global source byte offset instead.
#define STAGE_TILES(CB, K0)                                                   \
    {                                                                         \
        _Pragma("unroll")                                                     \
        for (int it = 0; it < 2; ++it) {                                      \
            const int f    = it * 256 + tid;                                  \
            const int row  = f >> 2;                                          \
            const int inn  = (((f & 3) ^ ((row >> 1) & 3))) * 16;             \
            const int loff = (CB) + (it * 256 + wave * 64) * 16;              \
            const signed char* ga = A1 + (size_t)(m0 + row) * HID2 + (K0) + inn; \
            __builtin_amdgcn_global_load_lds(                                 \
                (const __attribute__((address_space(1))) unsigned int*)ga,    \
                (__attribute__((address_space(3))) unsigned int*)(sAll + loff), \
                16, 0, 0);                                                    \
            const signed char* gb = A2 + (size_t)(m0 + row) * HID2 + (K0) + inn; \
            __builtin_amdgcn_global_load_lds(                                 \
                (const __attribute__((address_space(1))) unsigned int*)gb,    \
                (__attribute__((address_space(3))) unsigned int*)(sAll + 8192 + loff), \
                16, 0, 0);                                                    \
            const signed char* gc = B1 + (size_t)(h0 + row) * HID2 + (K0) + inn; \
            __builtin_amdgcn_global_load_lds(                                 \
                (const __attribute__((address_space(1))) unsigned int*)gc,    \
                (__attribute__((address_space(3))) unsigned int*)(sAll + 16384 + loff), \
                16, 0, 0);                                                    \
        }                                                                     \
    }

    // fused waits + barrier WITH memory semantics (see header comment)
#define SYNC_KEEP6() asm volatile("s_waitcnt vmcnt(6) lgkmcnt(0)\n\ts_barrier" ::: "memory")
#define SYNC_DRAIN() asm volatile("s_waitcnt vmcnt(0) lgkmcnt(0)\n\ts_barrier" ::: "memory")

    // ---- prologue: stage steps 0 and 1 (slots 0,1); drain only step 0 ----
    STAGE_TILES(0, 0);
    STAGE_TILES(24576, 64);
    SYNC_KEEP6();

    // pipe slots rotate: read cu; stage into pv (slot last read 2 steps ago)
    int pv = 2 * 24576, cu = 0, nx = 24576;
    for (int ks = 0; ks < 32; ++ks) {
        // 1) issue stage for step ks+2 (overlaps everything below; stays
        //    in flight across the end-of-step barrier thanks to vmcnt(6))
        if (ks < 30) STAGE_TILES(pv, (ks + 2) * 64);

        // 2) fragments from cu; compiler interleaves these with the MFMAs
        //    via its own fine-grained lgkmcnt
        i4v a1[4], a2[4], b1[4];
#pragma unroll
        for (int i = 0; i < 4; ++i) {
            const int ra = cu + (wm * 64 + i * 16 + ar) * 64 + ko;
            const int rb = cu + 16384 + (wn * 64 + i * 16 + ar) * 64 + ko;
            a1[i] = *(const i4v*)&sAll[ra];
            a2[i] = *(const i4v*)&sAll[8192 + ra];
            b1[i] = *(const i4v*)&sAll[rb];
        }
#pragma unroll
        for (int i = 0; i < 4; ++i)
#pragma unroll
            for (int j = 0; j < 4; ++j) {
                c1[i][j] = __builtin_amdgcn_mfma_i32_16x16x64_i8(a1[i], b1[j], c1[i][j], 0, 0, 0);
                c2[i][j] = __builtin_amdgcn_mfma_i32_16x16x64_i8(a2[i], b1[j], c2[i][j], 0, 0, 0);
            }

        // 3) counted wait + barrier (memory-ordered): step ks+1's loads must
        //    have landed; step ks+2's 6 remain outstanding across the barrier.
        if (ks < 30) SYNC_KEEP6(); else SYNC_DRAIN();
        const int t = cu; cu = nx; nx = pv; pv = t;
    }
#undef STAGE_TILES
#undef SYNC_KEEP6
#undef SYNC_DRAIN

    // ---- fused epilogue: C/D layout col=lane&15, row=(lane>>4)*4+reg ----
    const int col = lane & 15;
    const int rg  = lane >> 4;
    const float invs = 1.f / (4096.f * 5746.f);   // c2-scale; c1 carries x256
    float vj[4], ubj[4];
#pragma unroll
    for (int j = 0; j < 4; ++j) {
        const int hc = h0 + wn * 64 + j * 16 + col;
        vj[j]  = vw[hc];
        ubj[j] = Ub[hc];
    }
#pragma unroll
    for (int i = 0; i < 4; ++i) {
#pragma unroll
        for (int r = 0; r < 4; ++r) {
            const int mm = m0 + wm * 64 + i * 16 + rg * 4 + r;
            const int b  = (m_base + mm) & 63;
            const float* whr = Wh + b * HID + h0 + wn * 64 + col;
            float e = 0.f;
#pragma unroll
            for (int j = 0; j < 4; ++j) {
                float C = fmaf((float)c1[i][j][r], 256.f, (float)c2[i][j][r]) * invs;
                float x = C + ubj[j] + whr[j * 16];
                e += vj[j] * tanh_fast(x);
            }
            e += __shfl_xor(e, 1, 64);
            e += __shfl_xor(e, 2, 64);
            e += __shfl_xor(e, 4, 64);
            e += __shfl_xor(e, 8, 64);
            if (col == 0) atomicAdd(&energy[m_base + mm], e);
        }
    }
}

// ---------------------------------------------------------------------------
// K4: masked softmax over s per b. energy layout [s*64+b], out [b][s].
// ---------------------------------------------------------------------------
__global__ void softmax_kernel(const float* __restrict__ energy,
                               const int* __restrict__ mask,
                               float* __restrict__ out) {
    const int b = blockIdx.x;
    const int t = threadIdx.x;
    __shared__ float wmax[4], wsum[4];

    float x0 = energy[t * 64 + b];
    float x1 = energy[(t + 256) * 64 + b];
    float e0 = mask[b * SRC + t]       ? NEGV : x0;
    float e1 = mask[b * SRC + t + 256] ? NEGV : x1;

    float mx = fmaxf(e0, e1);
#pragma unroll
    for (int off = 1; off < 64; off <<= 1)
        mx = fmaxf(mx, __shfl_xor(mx, off, 64));
    const int wid = t >> 6, lane = t & 63;
    if (lane == 0) wmax[wid] = mx;
    __syncthreads();
    mx = fmaxf(fmaxf(wmax[0], wmax[1]), fmaxf(wmax[2], wmax[3]));

    float p0 = expf(e0 - mx), p1 = expf(e1 - mx);
    float sum = p0 + p1;
#pragma unroll
    for (int off = 1; off < 64; off <<= 1)
        sum += __shfl_xor(sum, off, 64);
    if (lane == 0) wsum[wid] = sum;
    __syncthreads();
    sum = wsum[0] + wsum[1] + wsum[2] + wsum[3];
    const float inv = 1.f / sum;
    out[b * SRC + t]       = p0 * inv;
    out[b * SRC + t + 256] = p1 * inv;
}

// ---------------------------------------------------------------------------
extern "C" void kernel_launch(void* const* d_in, const int* in_sizes, int n_in,
                              void* d_out, int out_size, void* d_ws, size_t ws_size,
                              hipStream_t stream) {
    const float* hidden = (const float*)d_in[0];   // [64, 1024]
    const float* enc    = (const float*)d_in[1];   // [512*64, 2048] flat rows
    const int*   mask   = (const int*)d_in[2];     // [64, 512]
    const float* W_w    = (const float*)d_in[3];   // [1024, 1024]
    const float* W_b    = (const float*)d_in[4];   // [1024]
    const float* U_w    = (const float*)d_in[5];   // [1024, 2048]
    const float* U_b    = (const float*)d_in[6];   // [1024]
    const float* v_w    = (const float*)d_in[7];   // [1, 1024]
    float* out = (float*)d_out;                    // [64, 512]

    // workspace layout
    char* p = (char*)d_ws;
    float* Wh     = (float*)p;             p += (size_t)BATCH * HID * 4;
    float* energy = (float*)p;             p += (size_t)MROWS * 4;
    signed char* B1 = (signed char*)p;     p += (size_t)HID * HID2;
    const size_t fixed = (size_t)(p - (char*)d_ws);

    // pick largest A-chunk R (multiple of 128 rows): bytes = 2 * R * 2048
    int R = 1024;
    const int cand[6] = {32768, 16384, 8192, 4096, 2048, 1024};
    for (int c = 0; c < 6; ++c) {
        if (fixed + (size_t)cand[c] * HID2 * 2 <= ws_size) { R = cand[c]; break; }
    }
    signed char* A1 = (signed char*)p;
    signed char* A2 = A1 + (size_t)R * HID2;

    // scales: a ~= A1/16 + A2/4096 ; b ~= B1/5746  (max-range single digit)
    const float Sa1 = 16.f, iSa1 = 1.f / 16.f, Sa2 = 4096.f;
    const float Sb1 = 5746.f;

    hipLaunchKernelGGL(zero_energy, dim3(MROWS / 256), dim3(256), 0, stream, energy);
    hipLaunchKernelGGL(wh_kernel, dim3(4, BATCH), dim3(256), 0, stream,
                       hidden, W_w, W_b, Wh);
    {   // quantize U_w once (8 MB fp32 -> 2 MB i8)
        const int n4 = HID * HID2 / 4;
        hipLaunchKernelGGL(quant_i8, dim3(1024), dim3(256), 0, stream,
                           U_w, B1, n4, Sb1);
    }
    for (int c0 = 0; c0 < MROWS; c0 += R) {
        const int n4 = R * HID2 / 4;
        hipLaunchKernelGGL(split_i8, dim3(2048), dim3(256), 0, stream,
                           enc + (size_t)c0 * HID2, A1, A2, n4, Sa1, iSa1, Sa2);
        hipLaunchKernelGGL(gemm_energy, dim3(HID / 128, R / 128), dim3(256), 0, stream,
                           A1, A2, B1, U_b, v_w, Wh, energy, c0);
    }
    hipLaunchKernelGGL(softmax_kernel, dim3(BATCH), dim3(256), 0, stream,
                       energy, mask, out);
}